// Round 6
// baseline (57750.378 us; speedup 1.0000x reference)
//
#include <hip/hip_runtime.h>

typedef unsigned short u16;
typedef unsigned int   u32;
typedef __bf16 bf16x8 __attribute__((ext_vector_type(8)));
typedef float  f32x4  __attribute__((ext_vector_type(4)));

#define T_SEQ 65536

__device__ __forceinline__ float bf2f(u16 v){ return __uint_as_float(((u32)v) << 16); }
__device__ __forceinline__ float bflo(u32 w){ return __uint_as_float(w << 16); }
__device__ __forceinline__ float bfhi(u32 w){ return __uint_as_float(w & 0xFFFF0000u); }
__device__ __forceinline__ u16 f2bf(float f){
  u32 u = __float_as_uint(f);
  u32 r = (u + 0x7FFFu + ((u >> 16) & 1u)) >> 16;
  return (u16)r;
}
__device__ __forceinline__ float sigm(float x){ return 1.0f / (1.0f + __expf(-x)); }
__device__ __forceinline__ float tanh_(float x){ return 1.0f - 2.0f / (1.0f + __expf(2.0f * x)); }

__device__ __forceinline__ float ldf(const void* p, size_t i, int f){
  return f ? ((const float*)p)[i] : bf2f(((const u16*)p)[i]);
}
__device__ __forceinline__ void stf(void* p, size_t i, float v, int f){
  if (f) ((float*)p)[i] = v; else ((u16*)p)[i] = f2bf(v);
}

__device__ __forceinline__ bf16x8 ldg_frag(const u16* p){
  uint4 v = *(const uint4*)p;
  return __builtin_bit_cast(bf16x8, v);
}
__device__ __forceinline__ bf16x8 load_frag_dyn(const void* p, int off, int f){
  if (!f) return ldg_frag((const u16*)p + off);
  union { u16 h[8]; bf16x8 v; } t;
  const float* q = (const float*)p + off;
#pragma unroll
  for (int j = 0; j < 8; ++j) t.h[j] = f2bf(q[j]);
  return t.v;
}
__device__ __forceinline__ bf16x8 lds_frag(const u16* p){
  uint4 v = *(const uint4*)p;
  return __builtin_bit_cast(bf16x8, v);
}

// LDS-only barrier: drains lgkmcnt but NOT vmcnt, so in-flight global prefetch
// loads / fire-and-forget h stores stay in flight across the step boundary.
__device__ __forceinline__ void bar_sync(){
  asm volatile("s_waitcnt lgkmcnt(0)" ::: "memory");
  __builtin_amdgcn_s_barrier();
  asm volatile("" ::: "memory");
}

// ---------------- K0: per-array dtype detector ----------------
struct Ptrs { const void* p[15]; int n[15]; };

__global__ void k_detect(Ptrs ptrs, int* flags){
  const int i = threadIdx.x;
  if (i >= 15) return;
  const u32* w = (const u32*)ptrs.p[i];
  int words = ptrs.n[i] >> 1; if (words > 256) words = 256;
  int bad = 0, good = 0;
  for (int j = 0; j < words; ++j){
    u32 lo = w[j] & 0xFFFFu;
    if (lo == 0) continue;
    u32 e = (lo >> 7) & 0xFFu;
    if (e >= 96 && e <= 135) ++good; else ++bad;
  }
  flags[i] = (bad > good) ? 1 : 0;
}

// ---------------- K1: preA[t][j-major] = x[t] @ WA1^T + bA1 + bA2 ----------
// Output layout J-MAJOR: out[t*512 + j*4 + gate]  (gate = r>>7, j = r&127)
// so the recurrence reads all 4 gates of one j with a single ds_read_b64.
__global__ __launch_bounds__(512) void k_gemm(const void* __restrict__ in, const void* __restrict__ W,
                                              const void* __restrict__ b1, const void* __restrict__ b2,
                                              const int* __restrict__ flags,
                                              int fiIn, int fiW, int fiB1, int fiB2,
                                              u16* __restrict__ out, int tbase){
  __shared__ __align__(16) float sx[32 * 128];
  const int fin = (fiIn < 0) ? 0 : flags[fiIn];
  const int fw = flags[fiW], f1 = flags[fiB1], f2 = flags[fiB2];
  const int tid = threadIdx.x;
  const int tl0 = blockIdx.x * 32;
  const int tg0 = tbase + tl0;
  for (int i = tid; i < 32 * 128; i += 512) sx[i] = ldf(in, (size_t)tg0 * 128 + i, fin);
  __syncthreads();
  const int r = tid;
  const int rr = ((r & 127) << 2) | (r >> 7); // j-major permuted index
  float bias = ldf(b1, r, f1) + ldf(b2, r, f2);
  float acc[32];
#pragma unroll
  for (int t = 0; t < 32; ++t) acc[t] = bias;
  if (!fw){
    const u32* wrow = (const u32*)W + r * 64;
    for (int c = 0; c < 32; ++c){
      uint2 wp = *(const uint2*)(wrow + 2 * c);
      float w0 = bflo(wp.x), w1 = bfhi(wp.x), w2 = bflo(wp.y), w3 = bfhi(wp.y);
#pragma unroll
      for (int t = 0; t < 32; ++t){
        const f32x4 xv = *(const f32x4*)&sx[t * 128 + 4 * c];
        acc[t] += w0 * xv.x + w1 * xv.y + w2 * xv.z + w3 * xv.w;
      }
    }
  } else {
    const float* wrow = (const float*)W + r * 128;
    for (int c = 0; c < 32; ++c){
      const f32x4 wv = *(const f32x4*)(wrow + 4 * c);
#pragma unroll
      for (int t = 0; t < 32; ++t){
        const f32x4 xv = *(const f32x4*)&sx[t * 128 + 4 * c];
        acc[t] += wv.x * xv.x + wv.y * xv.y + wv.z * xv.z + wv.w * xv.w;
      }
    }
  }
  for (int t = 0; t < 32; ++t) out[(size_t)(tl0 + t) * 512 + rr] = f2bf(acc[t]);
}

// ---------------- K2: 3-block pipelined dual recurrence (4 waves/block) ----
// Block 0: rec A (WA2). Block 1: preB producer (WB1). Block 2: rec B (WB2).
// 256 threads = 4 waves. Each rec wave owns 32 j's (2 MFMA tiles, 32 MFMAs)
// so block-wide LDS traffic halves vs 8-wave (LDS pipe is per-CU and was
// ~600 cy/step of the measured ~2000). Pre-gates are j-major: one
// ds_read_b64 fetches all 4 gates of a j.
// HANG-PROOF: all inter-block flag polls are bounded (~2 ms via
// s_memrealtime, >>100x the us-scale legit waits) with a per-block abort
// latch — a blocked handshake degrades to a terminating wrong-answer run
// (counters + failure signature) instead of a dead container.
__global__ __launch_bounds__(256, 1) void k_dual(
    const u16* __restrict__ preA, u16* __restrict__ preB,
    u16* __restrict__ hAws, u16* __restrict__ hb,
    const void* __restrict__ WA2, const void* __restrict__ WB1, const void* __restrict__ WB2,
    const void* __restrict__ hA0, const void* __restrict__ cA0,
    const void* __restrict__ hB0, const void* __restrict__ cB0,
    const void* __restrict__ bB1, const void* __restrict__ bB2,
    const int* __restrict__ flags, u32* __restrict__ flagA, u32* __restrict__ flagP,
    u16* __restrict__ stH, float* __restrict__ stC,
    void* __restrict__ outBase, int first, int last, int L)
{
  __shared__ __align__(16) u16 sPre[2][16 * 512]; // 32 KB double-buffered pre-gates
  __shared__ __align__(16) u16 sH[2][128];        // double-buffered h
  __shared__ u32 sAbort;                          // poll-timeout latch (tid0 only)

  const int tid = threadIdx.x;
  const int w = tid >> 6, l = tid & 63, q = l >> 4, m = l & 15;
  const int fo = flags[0];
  const int role = blockIdx.x;
  const int G = L >> 4;
  const unsigned long long PTO = 200000ull; // ~2 ms at 100 MHz RTC

  if (tid == 0) sAbort = 0u;

  if (role == 1){
    // ---------- preB producer: 4 waves, 8 row-tiles each ----------
    const int fW = flags[9], f1 = flags[10], f2 = flags[12];
    bf16x8 wf[8][4];
#pragma unroll
    for (int rt = 0; rt < 8; ++rt){
      const int row = (w * 8 + rt) * 16 + m;
#pragma unroll
      for (int kt = 0; kt < 4; ++kt)
        wf[rt][kt] = load_frag_dyn(WB1, row * 128 + kt * 32 + q * 8, fW);
    }
    float bias[8][4];
#pragma unroll
    for (int rt = 0; rt < 8; ++rt)
#pragma unroll
      for (int rg = 0; rg < 4; ++rg){
        const int r = (w * 8 + rt) * 16 + q * 4 + rg;
        bias[rt][rg] = ldf(bB1, r, f1) + ldf(bB2, r, f2);
      }
    for (int g = 0; g < G; ++g){
      if (tid == 0 && sAbort == 0u){
        const unsigned long long tt0 = __builtin_amdgcn_s_memrealtime();
        while (atomicAdd(&flagA[g], 0u) == 0u){
          __builtin_amdgcn_s_sleep(8);
          if (__builtin_amdgcn_s_memrealtime() - tt0 > PTO){ sAbort = 1u; break; }
        }
      }
      __syncthreads();
      const u16* hg = hAws + (size_t)g * 2048; // 16 rows x 128
      f32x4 acc[8];
#pragma unroll
      for (int rt = 0; rt < 8; ++rt) acc[rt] = (f32x4){0.f, 0.f, 0.f, 0.f};
#pragma unroll
      for (int kt = 0; kt < 4; ++kt){
        bf16x8 bfrag = ldg_frag(hg + m * 128 + kt * 32 + q * 8); // col m = timestep
#pragma unroll
        for (int rt = 0; rt < 8; ++rt)
          acc[rt] = __builtin_amdgcn_mfma_f32_16x16x32_bf16(wf[rt][kt], bfrag, acc[rt], 0, 0, 0);
      }
      const int tg = g * 16 + m;
#pragma unroll
      for (int rt = 0; rt < 8; ++rt)
#pragma unroll
        for (int rg = 0; rg < 4; ++rg){
          const int r = (w * 8 + rt) * 16 + q * 4 + rg;
          preB[(size_t)tg * 512 + (((r & 127) << 2) | (r >> 7))] =
              f2bf(acc[rt][rg] + bias[rt][rg]);
        }
      __threadfence();
      __syncthreads();
      if (tid == 0) atomicExch(&flagP[g], 1u);
    }
    return;
  }

  // ---------- roles 0 / 2: recurrence ----------
  const bool isA = (role == 0);
  const u16* pre = isA ? preA : preB;
  u16* hdump = isA ? hAws : hb;
  const void* Wm = isA ? WA2 : WB2;
  const void* h0 = isA ? hA0 : hB0;
  const void* c0 = isA ? cA0 : cB0;
  const int fW  = isA ? flags[7] : flags[11];
  const int fH0 = isA ? flags[1] : flags[3];
  const int fC0 = isA ? flags[2] : flags[4];
  const int sto = isA ? 0 : 128;

  // B-operand weight fragments, gate-major per tile:
  //   wave w owns j-tiles 2w, 2w+1; wf[ti][rt][kt] covers W rows
  //   rt*128 + (2w+ti)*16 + m  (tile col = lane m)
  bf16x8 wf[2][4][4];
#pragma unroll
  for (int ti = 0; ti < 2; ++ti)
#pragma unroll
    for (int rt = 0; rt < 4; ++rt){
      const int row = rt * 128 + (w * 2 + ti) * 16 + m;
#pragma unroll
      for (int kt = 0; kt < 4; ++kt)
        wf[ti][rt][kt] = load_frag_dyn(Wm, row * 128 + kt * 32 + q * 8, fW);
    }

  const int j0 = (w * 2) * 16 + m;  // tile 0 h-index
  const int j1 = j0 + 16;           // tile 1 h-index
  float c0_, c1_;
  if (first){
    c0_ = ldf(c0, j0, fC0);
    c1_ = ldf(c0, j1, fC0);
    if (tid < 128) sH[0][tid] = f2bf(ldf(h0, tid, fH0));
  } else {
    c0_ = stC[sto + j0];
    c1_ = stC[sto + j1];
    if (tid < 128) sH[0][tid] = stH[sto + tid];
  }

  // prologue: stage group 0 into sPre[0]
  if (!isA){
    if (tid == 0 && sAbort == 0u){
      const unsigned long long tt0 = __builtin_amdgcn_s_memrealtime();
      while (atomicAdd(&flagP[0], 0u) == 0u){
        __builtin_amdgcn_s_sleep(8);
        if (__builtin_amdgcn_s_memrealtime() - tt0 > PTO){ sAbort = 1u; break; }
      }
    }
    __syncthreads();
  }
  {
    const uint4* src = (const uint4*)pre;
    uint4* dst = (uint4*)&sPre[0][0];
#pragma unroll
    for (int i = 0; i < 4; ++i) dst[tid + 256 * i] = src[tid + 256 * i];
  }
  __syncthreads();

  uint4 st[4];
  int pend = 0, pbuf = 0;
  u16 hq0 = 0, hq1 = 0;

  for (int t = 0; t < L; ++t){
    const int slot = t & 15;
    const int g = t >> 4;
    const int buf = g & 1;
    const int rb = t & 1;

    if (slot == 0){
      if (isA){
        const int nc = g + 1;
        if (nc < G){
          const uint4* src = (const uint4*)pre;
#pragma unroll
          for (int i = 0; i < 4; ++i) st[i] = src[(size_t)nc * 1024 + tid + 256 * i];
          pend = 1; pbuf = nc & 1;
        }
      }
    } else if (slot == 1){
      if (!isA){
        const int nc = g + 1;
        if (nc < G){
          if (tid == 0 && sAbort == 0u){
            const unsigned long long tt0 = __builtin_amdgcn_s_memrealtime();
            while (atomicAdd(&flagP[nc], 0u) == 0u){
              __builtin_amdgcn_s_sleep(8);
              if (__builtin_amdgcn_s_memrealtime() - tt0 > PTO){ sAbort = 1u; break; }
            }
          }
          bar_sync();
          const uint4* src = (const uint4*)(pre + (size_t)nc * 8192);
#pragma unroll
          for (int i = 0; i < 4; ++i) st[i] = src[tid + 256 * i];
          pend = 1; pbuf = nc & 1;
        }
      }
    } else if (slot == 2){
      if (pend){
        uint4* dst = (uint4*)&sPre[pbuf][0];
#pragma unroll
        for (int i = 0; i < 4; ++i) dst[tid + 256 * i] = st[i];
        pend = 0;
      }
    } else if (slot == 3){
      // drain h stores of group g-1 (away from the prefetch issue at slot 0)
      if (isA && g > 0) __threadfence();
    } else if (slot == 4){
      // all waves fenced at slot 3, barrier passed -> safe to publish
      if (isA && g > 0 && tid == 192) atomicExch(&flagA[g - 1], 1u);
    }

    // pre-gate loads: one b64 per j (4 gates packed j-major)
    const uint2 pw0 = *(const uint2*)&sPre[buf][slot * 512 + j0 * 4];
    const uint2 pw1 = *(const uint2*)&sPre[buf][slot * 512 + j1 * 4];

    // A-operand: h(t-1) broadcast across rows
    bf16x8 bh[4];
#pragma unroll
    for (int kt = 0; kt < 4; ++kt) bh[kt] = lds_frag(&sH[rb][kt * 32 + q * 8]);

    f32x4 acc[2][4];
#pragma unroll
    for (int ti = 0; ti < 2; ++ti)
#pragma unroll
      for (int rt = 0; rt < 4; ++rt) acc[ti][rt] = (f32x4){0.f, 0.f, 0.f, 0.f};
#pragma unroll
    for (int kt = 0; kt < 4; ++kt)
#pragma unroll
      for (int ti = 0; ti < 2; ++ti)
#pragma unroll
        for (int rt = 0; rt < 4; ++rt)
          acc[ti][rt] = __builtin_amdgcn_mfma_f32_16x16x32_bf16(bh[kt], wf[ti][rt][kt], acc[ti][rt], 0, 0, 0);

    // cell tile 0 (gate rt for index j0 in acc[0][rt].x)
    {
      const float gi = sigm (bflo(pw0.x) + acc[0][0].x);
      const float gf = sigm (bfhi(pw0.x) + acc[0][1].x);
      const float gg = tanh_(bflo(pw0.y) + acc[0][2].x);
      const float go = sigm (bfhi(pw0.y) + acc[0][3].x);
      c0_ = gf * c0_ + gi * gg;
      hq0 = f2bf(go * tanh_(c0_));
    }
    // cell tile 1
    {
      const float gi = sigm (bflo(pw1.x) + acc[1][0].x);
      const float gf = sigm (bfhi(pw1.x) + acc[1][1].x);
      const float gg = tanh_(bflo(pw1.y) + acc[1][2].x);
      const float go = sigm (bfhi(pw1.y) + acc[1][3].x);
      c1_ = gf * c1_ + gi * gg;
      hq1 = f2bf(go * tanh_(c1_));
    }
    if (q == 0){
      sH[rb ^ 1][j0] = hq0;
      sH[rb ^ 1][j1] = hq1;
      hdump[(size_t)t * 128 + j0] = hq0; // fire-and-forget (vmcnt not drained)
      hdump[(size_t)t * 128 + j1] = hq1;
    }
    bar_sync();
  }

  // epilogue: release final group, persist state
  if (isA) __threadfence();
  __syncthreads();
  if (isA && tid == 0) atomicExch(&flagA[G - 1], 1u);
  if (q == 0){
    stC[sto + j0] = c0_;  stC[sto + j1] = c1_;
    stH[sto + j0] = hq0;  stH[sto + j1] = hq1;
    if (last){
      const size_t ob = (size_t)T_SEQ * 128;
      const size_t hOff = isA ? 0 : 256;
      const size_t cOff = isA ? 128 : 384;
      stf(outBase, ob + hOff + j0, bf2f(hq0), fo);
      stf(outBase, ob + hOff + j1, bf2f(hq1), fo);
      stf(outBase, ob + cOff + j0, c0_,       fo);
      stf(outBase, ob + cOff + j1, c1_,       fo);
    }
  }
}

// ---------------- K3: logits[t][v] = hb[t] @ Wfc^T + bfc ----------------
__global__ __launch_bounds__(256) void k_fc(const u16* __restrict__ hb,
                                            const void* __restrict__ Wfc, const void* __restrict__ bfc,
                                            const int* __restrict__ flags,
                                            void* __restrict__ out, int t0){
  __shared__ __align__(16) float sh[32 * 128];
  const int fw = flags[13], fb = flags[14], fo = flags[0];
  const int tid = threadIdx.x;
  const int tl0 = blockIdx.x * 32;
  for (int i = tid; i < 32 * 128; i += 256) sh[i] = bf2f(hb[(size_t)tl0 * 128 + i]);
  __syncthreads();
  const int v  = tid & 127;
  const int tt = tid >> 7;
  float bias = ldf(bfc, v, fb);
  float acc[16];
#pragma unroll
  for (int j = 0; j < 16; ++j) acc[j] = bias;
  if (!fw){
    const u32* wrow = (const u32*)Wfc + v * 64;
    for (int c = 0; c < 32; ++c){
      uint2 wp = *(const uint2*)(wrow + 2 * c);
      float w0 = bflo(wp.x), w1 = bfhi(wp.x), w2 = bflo(wp.y), w3 = bfhi(wp.y);
#pragma unroll
      for (int j = 0; j < 16; ++j){
        const f32x4 xv = *(const f32x4*)&sh[(tt + 2 * j) * 128 + 4 * c];
        acc[j] += w0 * xv.x + w1 * xv.y + w2 * xv.z + w3 * xv.w;
      }
    }
  } else {
    const float* wrow = (const float*)Wfc + v * 128;
    for (int c = 0; c < 32; ++c){
      const f32x4 wv = *(const f32x4*)(wrow + 4 * c);
#pragma unroll
      for (int j = 0; j < 16; ++j){
        const f32x4 xv = *(const f32x4*)&sh[(tt + 2 * j) * 128 + 4 * c];
        acc[j] += wv.x * xv.x + wv.y * xv.y + wv.z * xv.z + wv.w * xv.w;
      }
    }
  }
  for (int j = 0; j < 16; ++j)
    stf(out, (size_t)(t0 + tl0 + tt + 2 * j) * 128 + v, acc[j], fo);
}

extern "C" void kernel_launch(void* const* d_in, const int* in_sizes, int n_in,
                              void* d_out, int out_size, void* d_ws, size_t ws_size,
                              hipStream_t stream) {
  // ---- ws layout ----
  // [0,1024)      stC  (f32: A at 0..127, B at 128..255)
  // [1024,1536)   stH  (bf16: A, B)
  // [1536,1600)   dtype flags (int[16])
  // [2048, +4G)   flagA ; [+4G, +8G) flagP      (G = CHUNK/16)
  // dataOff:      preA [CHUNK*1024] | preB [CHUNK*1024] | hAws [CHUNK*256] | hb [CHUNK*256]
  int CHUNK = 32;
  size_t dataOff = 4096;
  for (int c = T_SEQ; c >= 32; c >>= 1){
    size_t G = (size_t)c / 16;
    size_t dOff = (2048 + 8 * G + 4095) & ~(size_t)4095;
    size_t need = dOff + (size_t)c * 2560;
    if (need <= ws_size){ CHUNK = c; dataOff = dOff; break; }
  }
  const size_t G = (size_t)CHUNK / 16;
  float* stC    = (float*)d_ws;
  u16*   stH    = (u16*)((char*)d_ws + 1024);
  int*   dflags = (int*)((char*)d_ws + 1536);
  u32*   flagA  = (u32*)((char*)d_ws + 2048);
  u32*   flagP  = (u32*)((char*)d_ws + 2048 + 4 * G);
  u16*   preA   = (u16*)((char*)d_ws + dataOff);
  u16*   preB   = (u16*)((char*)d_ws + dataOff + (size_t)CHUNK * 1024);
  u16*   hAws   = (u16*)((char*)d_ws + dataOff + (size_t)CHUNK * 2048);
  u16*   hb     = (u16*)((char*)d_ws + dataOff + (size_t)CHUNK * 2048 + (size_t)CHUNK * 256);

  Ptrs ptrs;
  for (int i = 0; i < 15; ++i){ ptrs.p[i] = d_in[i]; ptrs.n[i] = in_sizes[i]; }
  k_detect<<<1, 64, 0, stream>>>(ptrs, dflags);

  const int nChunks = T_SEQ / CHUNK;
  for (int c = 0; c < nChunks; ++c){
    const int t0 = c * CHUNK;
    const int first = (c == 0), last = (c == nChunks - 1);
    hipMemsetAsync(flagA, 0, 8 * G, stream);
    k_gemm<<<CHUNK / 32, 512, 0, stream>>>(d_in[0], d_in[5], d_in[6], d_in[8], dflags,
                                           0, 5, 6, 8, preA, t0);
    k_dual<<<3, 256, 0, stream>>>(preA, preB, hAws, hb,
                                  d_in[7], d_in[9], d_in[11],
                                  d_in[1], d_in[2], d_in[3], d_in[4],
                                  d_in[10], d_in[12],
                                  dflags, flagA, flagP, stH, stC,
                                  d_out, first, last, CHUNK);
    k_fc  <<<CHUNK / 32, 256, 0, stream>>>(hb, d_in[13], d_in[14], dflags, d_out, t0);
  }
}